// Round 2
// baseline (1229.682 us; speedup 1.0000x reference)
//
#include <hip/hip_runtime.h>

#define NN 50000
#define NE 600000
#define DD 128
#define HR 132   // LDS H row stride in elems (264 B, 16B-aligned)

typedef unsigned short u16;
typedef u16   u16x8  __attribute__((ext_vector_type(8)));
typedef u16   u16x4  __attribute__((ext_vector_type(4)));
typedef __bf16 bf16x8 __attribute__((ext_vector_type(8)));
typedef float f32x4  __attribute__((ext_vector_type(4)));

__device__ __forceinline__ u16 f2bf(float f) {  // RNE fp32->bf16
    unsigned u = __builtin_bit_cast(unsigned, f);
    u += 0x7FFFu + ((u >> 16) & 1u);
    return (u16)(u >> 16);
}
__device__ __forceinline__ bf16x8 ldbf8(const u16* p) {
    return __builtin_bit_cast(bf16x8, *(const u16x8*)p);
}

// Pack W[K,N] fp32 row-major into MFMA fragment order (A and B lane maps are
// identical on gfx950: m/n = lane&15, k = (lane>>4)*8 + j). frag = nt*(K/32)+kt.
__device__ __forceinline__ void pack_elem(const float* __restrict__ W,
                                          u16* __restrict__ out, int tid, int K, int N) {
    int frag = tid >> 9, lane = (tid >> 3) & 63, j = tid & 7;
    int KT = K >> 5;
    int nt = frag / KT, kt = frag - nt * KT;
    int row = kt * 32 + ((lane >> 4) << 3) + j;
    int col = nt * 16 + (lane & 15);
    out[tid] = f2bf(W[row * N + col]);
}

// One fused prep launch: nf fp32->bf16, zero agg, pack all 4 weight matrices.
__global__ __launch_bounds__(256) void k_prep(
    const float* __restrict__ nf, u16* __restrict__ nf16, float* __restrict__ agg,
    const float* __restrict__ mW0, u16* __restrict__ pmW0,
    const float* __restrict__ mW1, u16* __restrict__ pmW1,
    const float* __restrict__ uW0, u16* __restrict__ puW0,
    const float* __restrict__ uW1, u16* __restrict__ puW1)
{
    int t = blockIdx.x * 256 + threadIdx.x;
    if (t < 1600000) {                       // NN*DD/4 float4 chunks
        float4 v = ((const float4*)nf)[t];
        u16x4 o; o[0] = f2bf(v.x); o[1] = f2bf(v.y); o[2] = f2bf(v.z); o[3] = f2bf(v.w);
        ((u16x4*)nf16)[t] = o;
        ((float4*)agg)[t] = make_float4(0.f, 0.f, 0.f, 0.f);
        return;
    }
    t -= 1600000;
    if (t < 65536) { pack_elem(mW0, pmW0, t, 256, 256); return; }
    t -= 65536;
    if (t < 32768) { pack_elem(mW1, pmW1, t, 256, 128); return; }
    t -= 32768;
    if (t < 65536) { pack_elem(uW0, puW0, t, 256, 256); return; }
    t -= 65536;
    if (t < 32768) { pack_elem(uW1, puW1, t, 256, 128); }
}

// Edge kernel, operand-swapped: H^T = W0^T . X^T ; M^T = W1^T . H^T.
// 3 waves/block, 32 edges/wave (2 n-tiles), no __syncthreads, H staged per
// 128-col half in wave-private LDS, layer-1 acc persistent in VGPRs.
__global__ __launch_bounds__(192, 3) void k_edges(
    const u16* __restrict__ nf16, const int* __restrict__ from_idx,
    const int* __restrict__ to_idx, const u16* __restrict__ pW0,
    const float* __restrict__ b0, const u16* __restrict__ pW1,
    const float* __restrict__ b1, float* __restrict__ agg)
{
    __shared__ u16 sH[3 * 32 * HR];
    const int tid  = threadIdx.x;
    const int wave = tid >> 6, lane = tid & 63;
    const int l15  = lane & 15, quad = lane >> 4;
    const int e0   = blockIdx.x * 96 + wave * 32;
    const int co   = quad * 8;

    const int iF0 = from_idx[e0 + l15];
    const int iF1 = from_idx[e0 + 16 + l15];
    const int iT0 = to_idx[e0 + l15];
    const int iT1 = to_idx[e0 + 16 + l15];

    // X gathered straight into B-fragments (k = quad*8+j ... +kt*32)
    bf16x8 x0[8], x1[8];
    #pragma unroll
    for (int kt = 0; kt < 4; ++kt) {
        x0[kt]     = ldbf8(nf16 + iF0 * DD + kt * 32 + co);
        x0[kt + 4] = ldbf8(nf16 + iT0 * DD + kt * 32 + co);
        x1[kt]     = ldbf8(nf16 + iF1 * DD + kt * 32 + co);
        x1[kt + 4] = ldbf8(nf16 + iT1 * DD + kt * 32 + co);
    }

    f32x4 acc1[2][8];
    #pragma unroll
    for (int m = 0; m < 2; ++m)
        #pragma unroll
        for (int n = 0; n < 8; ++n) acc1[m][n] = (f32x4){0.f, 0.f, 0.f, 0.f};

    u16* myH = sH + wave * (32 * HR);

    #pragma unroll
    for (int h = 0; h < 2; ++h) {
        // layer 0, feature tiles nt = 8h..8h+7 -> H cols 128h..128h+127
        #pragma unroll
        for (int ntl = 0; ntl < 8; ++ntl) {
            const int nt = h * 8 + ntl;
            const u16* wp = pW0 + (nt * 8) * 512 + lane * 8;
            f32x4 c0 = {0.f,0.f,0.f,0.f}, c1 = {0.f,0.f,0.f,0.f};
            #pragma unroll
            for (int kt = 0; kt < 8; ++kt) {
                bf16x8 a = ldbf8(wp + kt * 512);
                c0 = __builtin_amdgcn_mfma_f32_16x16x32_bf16(a, x0[kt], c0, 0, 0, 0);
                c1 = __builtin_amdgcn_mfma_f32_16x16x32_bf16(a, x1[kt], c1, 0, 0, 0);
            }
            const float4 bs = *(const float4*)(b0 + nt * 16 + quad * 4);
            u16x4 p0, p1;
            p0[0] = f2bf(fmaxf(c0[0] + bs.x, 0.f)); p0[1] = f2bf(fmaxf(c0[1] + bs.y, 0.f));
            p0[2] = f2bf(fmaxf(c0[2] + bs.z, 0.f)); p0[3] = f2bf(fmaxf(c0[3] + bs.w, 0.f));
            p1[0] = f2bf(fmaxf(c1[0] + bs.x, 0.f)); p1[1] = f2bf(fmaxf(c1[1] + bs.y, 0.f));
            p1[2] = f2bf(fmaxf(c1[2] + bs.z, 0.f)); p1[3] = f2bf(fmaxf(c1[3] + bs.w, 0.f));
            // edge-major H: lane holds 4 consecutive features of edge l15 -> b64 write
            *(u16x4*)(myH + l15 * HR        + ntl * 16 + quad * 4) = p0;
            *(u16x4*)(myH + (16 + l15) * HR + ntl * 16 + quad * 4) = p1;
        }
        // layer 1 partial: kt1 = 4h..4h+3 (wave-private rows: in-wave DS ordering, no barrier)
        #pragma unroll
        for (int c = 0; c < 4; ++c) {
            const int kt1 = h * 4 + c;
            bf16x8 h0 = ldbf8(myH + l15 * HR        + c * 32 + co);
            bf16x8 h1 = ldbf8(myH + (16 + l15) * HR + c * 32 + co);
            const u16* wp1 = pW1 + kt1 * 512 + lane * 8;
            #pragma unroll
            for (int n = 0; n < 8; ++n) {
                bf16x8 a = ldbf8(wp1 + n * 8 * 512);
                acc1[0][n] = __builtin_amdgcn_mfma_f32_16x16x32_bf16(a, h0, acc1[0][n], 0, 0, 0);
                acc1[1][n] = __builtin_amdgcn_mfma_f32_16x16x32_bf16(a, h1, acc1[1][n], 0, 0, 0);
            }
        }
    }
    // epilogue: bias+relu, 4 consecutive floats per lane, fire-and-forget atomics
    #pragma unroll
    for (int n = 0; n < 8; ++n) {
        const float4 bs = *(const float4*)(b1 + n * 16 + quad * 4);
        float* p0 = agg + iT0 * DD + n * 16 + quad * 4;
        float* p1 = agg + iT1 * DD + n * 16 + quad * 4;
        unsafeAtomicAdd(p0 + 0, fmaxf(acc1[0][n][0] + bs.x, 0.f));
        unsafeAtomicAdd(p0 + 1, fmaxf(acc1[0][n][1] + bs.y, 0.f));
        unsafeAtomicAdd(p0 + 2, fmaxf(acc1[0][n][2] + bs.z, 0.f));
        unsafeAtomicAdd(p0 + 3, fmaxf(acc1[0][n][3] + bs.w, 0.f));
        unsafeAtomicAdd(p1 + 0, fmaxf(acc1[1][n][0] + bs.x, 0.f));
        unsafeAtomicAdd(p1 + 1, fmaxf(acc1[1][n][1] + bs.y, 0.f));
        unsafeAtomicAdd(p1 + 2, fmaxf(acc1[1][n][2] + bs.z, 0.f));
        unsafeAtomicAdd(p1 + 3, fmaxf(acc1[1][n][3] + bs.w, 0.f));
    }
}

// Node update, same skeleton: out = nf + relu(relu([agg|nf] W0 + b0) W1 + b1)
__global__ __launch_bounds__(192, 3) void k_update(
    const float* __restrict__ agg, const u16* __restrict__ nf16,
    const float* __restrict__ nf32, const u16* __restrict__ pW0,
    const float* __restrict__ b0, const u16* __restrict__ pW1,
    const float* __restrict__ b1, float* __restrict__ out)
{
    __shared__ u16 sH[3 * 32 * HR];
    const int tid  = threadIdx.x;
    const int wave = tid >> 6, lane = tid & 63;
    const int l15  = lane & 15, quad = lane >> 4;
    const int n0   = blockIdx.x * 96 + wave * 32;
    const int co   = quad * 8;

    const int nA = n0 + l15, nB = n0 + 16 + l15;
    const bool vA = nA < NN, vB = nB < NN;
    const int cA = vA ? nA : 0, cB = vB ? nB : 0;

    bf16x8 x0[8], x1[8];
    #pragma unroll
    for (int kt = 0; kt < 4; ++kt) {  // cols 0..127: agg (fp32 -> bf16 on the fly)
        const float* pa = agg + cA * DD + kt * 32 + co;
        const float* pb = agg + cB * DD + kt * 32 + co;
        float4 ua = *(const float4*)pa, va = *(const float4*)(pa + 4);
        float4 ub = *(const float4*)pb, vb = *(const float4*)(pb + 4);
        u16x8 ta, tb;
        ta[0]=f2bf(ua.x); ta[1]=f2bf(ua.y); ta[2]=f2bf(ua.z); ta[3]=f2bf(ua.w);
        ta[4]=f2bf(va.x); ta[5]=f2bf(va.y); ta[6]=f2bf(va.z); ta[7]=f2bf(va.w);
        tb[0]=f2bf(ub.x); tb[1]=f2bf(ub.y); tb[2]=f2bf(ub.z); tb[3]=f2bf(ub.w);
        tb[4]=f2bf(vb.x); tb[5]=f2bf(vb.y); tb[6]=f2bf(vb.z); tb[7]=f2bf(vb.w);
        x0[kt] = __builtin_bit_cast(bf16x8, ta);
        x1[kt] = __builtin_bit_cast(bf16x8, tb);
    }
    #pragma unroll
    for (int kt = 0; kt < 4; ++kt) {  // cols 128..255: node features (bf16)
        x0[kt + 4] = ldbf8(nf16 + cA * DD + kt * 32 + co);
        x1[kt + 4] = ldbf8(nf16 + cB * DD + kt * 32 + co);
    }

    f32x4 acc1[2][8];
    #pragma unroll
    for (int m = 0; m < 2; ++m)
        #pragma unroll
        for (int n = 0; n < 8; ++n) acc1[m][n] = (f32x4){0.f, 0.f, 0.f, 0.f};

    u16* myH = sH + wave * (32 * HR);

    #pragma unroll
    for (int h = 0; h < 2; ++h) {
        #pragma unroll
        for (int ntl = 0; ntl < 8; ++ntl) {
            const int nt = h * 8 + ntl;
            const u16* wp = pW0 + (nt * 8) * 512 + lane * 8;
            f32x4 c0 = {0.f,0.f,0.f,0.f}, c1 = {0.f,0.f,0.f,0.f};
            #pragma unroll
            for (int kt = 0; kt < 8; ++kt) {
                bf16x8 a = ldbf8(wp + kt * 512);
                c0 = __builtin_amdgcn_mfma_f32_16x16x32_bf16(a, x0[kt], c0, 0, 0, 0);
                c1 = __builtin_amdgcn_mfma_f32_16x16x32_bf16(a, x1[kt], c1, 0, 0, 0);
            }
            const float4 bs = *(const float4*)(b0 + nt * 16 + quad * 4);
            u16x4 p0, p1;
            p0[0] = f2bf(fmaxf(c0[0] + bs.x, 0.f)); p0[1] = f2bf(fmaxf(c0[1] + bs.y, 0.f));
            p0[2] = f2bf(fmaxf(c0[2] + bs.z, 0.f)); p0[3] = f2bf(fmaxf(c0[3] + bs.w, 0.f));
            p1[0] = f2bf(fmaxf(c1[0] + bs.x, 0.f)); p1[1] = f2bf(fmaxf(c1[1] + bs.y, 0.f));
            p1[2] = f2bf(fmaxf(c1[2] + bs.z, 0.f)); p1[3] = f2bf(fmaxf(c1[3] + bs.w, 0.f));
            *(u16x4*)(myH + l15 * HR        + ntl * 16 + quad * 4) = p0;
            *(u16x4*)(myH + (16 + l15) * HR + ntl * 16 + quad * 4) = p1;
        }
        #pragma unroll
        for (int c = 0; c < 4; ++c) {
            const int kt1 = h * 4 + c;
            bf16x8 h0 = ldbf8(myH + l15 * HR        + c * 32 + co);
            bf16x8 h1 = ldbf8(myH + (16 + l15) * HR + c * 32 + co);
            const u16* wp1 = pW1 + kt1 * 512 + lane * 8;
            #pragma unroll
            for (int n = 0; n < 8; ++n) {
                bf16x8 a = ldbf8(wp1 + n * 8 * 512);
                acc1[0][n] = __builtin_amdgcn_mfma_f32_16x16x32_bf16(a, h0, acc1[0][n], 0, 0, 0);
                acc1[1][n] = __builtin_amdgcn_mfma_f32_16x16x32_bf16(a, h1, acc1[1][n], 0, 0, 0);
            }
        }
    }
    #pragma unroll
    for (int n = 0; n < 8; ++n) {
        const float4 bs = *(const float4*)(b1 + n * 16 + quad * 4);
        if (vA) {
            const float* r = nf32 + nA * DD + n * 16 + quad * 4;
            float4 o = *(const float4*)r;
            float4 w;
            w.x = o.x + fmaxf(acc1[0][n][0] + bs.x, 0.f);
            w.y = o.y + fmaxf(acc1[0][n][1] + bs.y, 0.f);
            w.z = o.z + fmaxf(acc1[0][n][2] + bs.z, 0.f);
            w.w = o.w + fmaxf(acc1[0][n][3] + bs.w, 0.f);
            *(float4*)(out + nA * DD + n * 16 + quad * 4) = w;
        }
        if (vB) {
            const float* r = nf32 + nB * DD + n * 16 + quad * 4;
            float4 o = *(const float4*)r;
            float4 w;
            w.x = o.x + fmaxf(acc1[1][n][0] + bs.x, 0.f);
            w.y = o.y + fmaxf(acc1[1][n][1] + bs.y, 0.f);
            w.z = o.z + fmaxf(acc1[1][n][2] + bs.z, 0.f);
            w.w = o.w + fmaxf(acc1[1][n][3] + bs.w, 0.f);
            *(float4*)(out + nB * DD + n * 16 + quad * 4) = w;
        }
    }
}

extern "C" void kernel_launch(void* const* d_in, const int* in_sizes, int n_in,
                              void* d_out, int out_size, void* d_ws, size_t ws_size,
                              hipStream_t stream)
{
    const float* nf  = (const float*)d_in[0];
    const int* fidx  = (const int*)d_in[1];
    const int* tidx  = (const int*)d_in[2];
    const float* mW0 = (const float*)d_in[3];
    const float* mb0 = (const float*)d_in[4];
    const float* mW1 = (const float*)d_in[5];
    const float* mb1 = (const float*)d_in[6];
    const float* uW0 = (const float*)d_in[7];
    const float* ub0 = (const float*)d_in[8];
    const float* uW1 = (const float*)d_in[9];
    const float* ub1 = (const float*)d_in[10];
    float* out = (float*)d_out;

    char* ws = (char*)d_ws;
    u16*   nf16 = (u16*)ws;   ws += (size_t)NN * DD * 2;   // 12.8 MB
    float* agg  = (float*)ws; ws += (size_t)NN * DD * 4;   // 25.6 MB
    u16*   pmW0 = (u16*)ws;   ws += 256 * 256 * 2;
    u16*   pmW1 = (u16*)ws;   ws += 256 * 128 * 2;
    u16*   puW0 = (u16*)ws;   ws += 256 * 256 * 2;
    u16*   puW1 = (u16*)ws;   ws += 256 * 128 * 2;

    // 1,600,000 convert/zero threads + 196,608 pack threads
    k_prep<<<7019, 256, 0, stream>>>(nf, nf16, agg, mW0, pmW0, mW1, pmW1, uW0, puW0, uW1, puW1);
    k_edges<<<NE / 96, 192, 0, stream>>>(nf16, fidx, tidx, pmW0, mb0, pmW1, mb1, agg);
    k_update<<<(NN + 95) / 96, 192, 0, stream>>>(agg, nf16, nf, puW0, ub0, puW1, ub1, out);
}

// Round 4
// 509.043 us; speedup vs baseline: 2.4157x; 2.4157x over previous
//
#include <hip/hip_runtime.h>

#define NN 50000
#define NE 600000
#define DD 128
#define HR 260   // k_update LDS H row stride (elems): 520 B, 8B-aligned, conflict-free b16 writes, 4-way b64 reads

typedef unsigned short u16;
typedef unsigned int   u32;
typedef u16   u16x8  __attribute__((ext_vector_type(8)));
typedef u16   u16x4  __attribute__((ext_vector_type(4)));
typedef u32   u32x4  __attribute__((ext_vector_type(4)));
typedef __bf16 bf16x8 __attribute__((ext_vector_type(8)));
typedef float f32x4  __attribute__((ext_vector_type(4)));

__device__ __forceinline__ u16 f2bf(float f) {  // RNE fp32->bf16
    unsigned u = __builtin_bit_cast(unsigned, f);
    u += 0x7FFFu + ((u >> 16) & 1u);
    return (u16)(u >> 16);
}
__device__ __forceinline__ float bf2f(u16 v) {
    return __builtin_bit_cast(float, (unsigned)v << 16);
}
__device__ __forceinline__ bf16x8 ldbf8(const u16* p) {
    return __builtin_bit_cast(bf16x8, *(const u16x8*)p);
}
__device__ __forceinline__ u32 pk2(float a, float b) {  // two floats -> packed bf16x2 (RNE)
    return (u32)f2bf(a) | ((u32)f2bf(b) << 16);
}

// Standard pack: W[K,N] fp32 row-major -> MFMA fragment order, frag = nt*(K/32)+kt,
// elem (lane,j) = W[kt*32+(lane>>4)*8+j][nt*16+(lane&15)]
__device__ __forceinline__ void pack_elem(const float* __restrict__ W,
                                          u16* __restrict__ out, int tid, int K, int N) {
    int frag = tid >> 9, lane = (tid >> 3) & 63, j = tid & 7;
    int KT = K >> 5;
    int nt = frag / KT, kt = frag - nt * KT;
    int row = kt * 32 + ((lane >> 4) << 3) + j;
    int col = nt * 16 + (lane & 15);
    out[tid] = f2bf(W[row * N + col]);
}

// One fused prep: nf->bf16, zero agg, pack Wcat=[mW0top|mW0bot](128x512), mW1, uW0, uW1.
__global__ __launch_bounds__(256) void k_prep(
    const float* __restrict__ nf, u16* __restrict__ nf16, float* __restrict__ agg,
    const float* __restrict__ mW0, u16* __restrict__ pWcat,
    const float* __restrict__ mW1, u16* __restrict__ pmW1,
    const float* __restrict__ uW0, u16* __restrict__ puW0,
    const float* __restrict__ uW1, u16* __restrict__ puW1)
{
    int t = blockIdx.x * 256 + threadIdx.x;
    if (t < 1600000) {                       // NN*DD/4 float4 chunks
        float4 v = ((const float4*)nf)[t];
        u16x4 o; o[0] = f2bf(v.x); o[1] = f2bf(v.y); o[2] = f2bf(v.z); o[3] = f2bf(v.w);
        ((u16x4*)nf16)[t] = o;
        ((float4*)agg)[t] = make_float4(0.f, 0.f, 0.f, 0.f);
        return;
    }
    t -= 1600000;
    if (t < 65536) {   // Wcat: K=128, N=512 (nt<16: W0 rows 0..127; nt>=16: rows 128..255)
        int frag = t >> 9, lane = (t >> 3) & 63, j = t & 7;
        int nt = frag >> 2, kt = frag & 3;
        int rl = kt * 32 + ((lane >> 4) << 3) + j;
        int cl = lane & 15;
        int row = (nt < 16) ? rl : (128 + rl);
        int col = (nt < 16) ? (nt * 16 + cl) : ((nt - 16) * 16 + cl);
        pWcat[t] = f2bf(mW0[row * 256 + col]);
        return;
    }
    t -= 65536;
    if (t < 32768) { pack_elem(mW1, pmW1, t, 256, 128); return; }
    t -= 32768;
    if (t < 65536) { pack_elem(uW0, puW0, t, 256, 256); return; }
    t -= 65536;
    if (t < 32768) { pack_elem(uW1, puW1, t, 256, 128); }
}

// P2[n][0:256]  = nf[n] . W0top + b0   (message layer-0 "from" partial, bias baked)
// P2[n][256:512]= nf[n] . W0bot        (message layer-0 "to" partial)
__global__ __launch_bounds__(192, 4) void k_pgemm(
    const u16* __restrict__ nf16, const float* __restrict__ mb0,
    const u16* __restrict__ pWcat, u16* __restrict__ P2)
{
    const int tid = threadIdx.x;
    const int wave = tid >> 6, lane = tid & 63;
    const int l15 = lane & 15, quad = lane >> 4;
    const int nb = blockIdx.x * 96 + wave * 32;
    const int co = quad * 8;

    bf16x8 x[2][4];
    #pragma unroll
    for (int m = 0; m < 2; ++m) {
        int node = nb + m * 16 + l15;
        int cn = (node < NN) ? node : 0;
        #pragma unroll
        for (int kt = 0; kt < 4; ++kt)
            x[m][kt] = ldbf8(nf16 + (size_t)cn * DD + kt * 32 + co);
    }
    for (int nt = 0; nt < 32; ++nt) {
        const u16* wp = pWcat + nt * 4 * 512 + lane * 8;
        f32x4 c0 = {0.f,0.f,0.f,0.f}, c1 = {0.f,0.f,0.f,0.f};
        #pragma unroll
        for (int kt = 0; kt < 4; ++kt) {
            bf16x8 b = ldbf8(wp + kt * 512);
            c0 = __builtin_amdgcn_mfma_f32_16x16x32_bf16(x[0][kt], b, c0, 0, 0, 0);
            c1 = __builtin_amdgcn_mfma_f32_16x16x32_bf16(x[1][kt], b, c1, 0, 0, 0);
        }
        float bias = (nt < 16) ? mb0[nt * 16 + l15] : 0.f;
        #pragma unroll
        for (int i = 0; i < 4; ++i) {
            int r0 = nb + quad * 4 + i;
            int r1 = nb + 16 + quad * 4 + i;
            if (r0 < NN) P2[(size_t)r0 * 512 + nt * 16 + l15] = f2bf(c0[i] + bias);
            if (r1 < NN) P2[(size_t)r1 * 512 + nt * 16 + l15] = f2bf(c1[i] + bias);
        }
    }
}

// Edge kernel: H-frag built in registers from gathered P rows (edges in M), layer-1 MFMA,
// coalesced atomic scatter. No LDS, no barriers.
__global__ __launch_bounds__(192, 3) void k_edges(
    const u16* __restrict__ P2, const int* __restrict__ from_idx,
    const int* __restrict__ to_idx, const u16* __restrict__ pW1,
    const float* __restrict__ b1, float* __restrict__ agg)
{
    const int tid = threadIdx.x;
    const int wave = tid >> 6, lane = tid & 63;
    const int l15 = lane & 15, quad = lane >> 4;
    const int e0 = blockIdx.x * 96 + wave * 32;
    const int co = quad * 8;

    const size_t f0 = (size_t)from_idx[e0 + l15] * 512;
    const size_t t0 = (size_t)to_idx[e0 + l15] * 512 + 256;
    const size_t f1 = (size_t)from_idx[e0 + 16 + l15] * 512;
    const size_t t1 = (size_t)to_idx[e0 + 16 + l15] * 512 + 256;

    f32x4 acc[2][8];
    #pragma unroll
    for (int m = 0; m < 2; ++m)
        #pragma unroll
        for (int n = 0; n < 8; ++n) acc[m][n] = (f32x4){0.f, 0.f, 0.f, 0.f};

    u16x8 ra = *(const u16x8*)(P2 + f0 + co);
    u16x8 rb = *(const u16x8*)(P2 + t0 + co);
    u16x8 rc = *(const u16x8*)(P2 + f1 + co);
    u16x8 rd = *(const u16x8*)(P2 + t1 + co);

    #pragma unroll
    for (int kt = 0; kt < 8; ++kt) {
        u16x8 na, nb_, nc, nd;
        if (kt < 7) {
            int o = (kt + 1) * 32 + co;
            na  = *(const u16x8*)(P2 + f0 + o);
            nb_ = *(const u16x8*)(P2 + t0 + o);
            nc  = *(const u16x8*)(P2 + f1 + o);
            nd  = *(const u16x8*)(P2 + t1 + o);
        }
        u32x4 q0, q1;
        #pragma unroll
        for (int e = 0; e < 4; ++e) {
            float s0 = bf2f(ra[2*e])   + bf2f(rb[2*e]);
            float s1 = bf2f(ra[2*e+1]) + bf2f(rb[2*e+1]);
            q0[e] = pk2(fmaxf(s0, 0.f), fmaxf(s1, 0.f));
            float u0 = bf2f(rc[2*e])   + bf2f(rd[2*e]);
            float u1 = bf2f(rc[2*e+1]) + bf2f(rd[2*e+1]);
            q1[e] = pk2(fmaxf(u0, 0.f), fmaxf(u1, 0.f));
        }
        bf16x8 h0 = __builtin_bit_cast(bf16x8, q0);
        bf16x8 h1 = __builtin_bit_cast(bf16x8, q1);
        const u16* wp = pW1 + kt * 512 + lane * 8;
        #pragma unroll
        for (int n = 0; n < 8; ++n) {
            bf16x8 w = ldbf8(wp + n * 4096);
            acc[0][n] = __builtin_amdgcn_mfma_f32_16x16x32_bf16(h0, w, acc[0][n], 0, 0, 0);
            acc[1][n] = __builtin_amdgcn_mfma_f32_16x16x32_bf16(h1, w, acc[1][n], 0, 0, 0);
        }
        ra = na; rb = nb_; rc = nc; rd = nd;
    }

    int tIe[2][4];
    #pragma unroll
    for (int m = 0; m < 2; ++m)
        #pragma unroll
        for (int i = 0; i < 4; ++i)
            tIe[m][i] = to_idx[e0 + m * 16 + quad * 4 + i];

    #pragma unroll
    for (int n = 0; n < 8; ++n) {
        float bs = b1[n * 16 + l15];
        #pragma unroll
        for (int m = 0; m < 2; ++m)
            #pragma unroll
            for (int i = 0; i < 4; ++i)
                unsafeAtomicAdd(agg + (size_t)tIe[m][i] * DD + n * 16 + l15,
                                fmaxf(acc[m][n][i] + bs, 0.f));
    }
}

// Node update, M-layout: out = nf + relu(relu([agg|nf] uW0 + ub0) uW1 + ub1)
__global__ __launch_bounds__(128, 3) void k_update(
    const float* __restrict__ agg, const u16* __restrict__ nf16,
    const float* __restrict__ nf32, const u16* __restrict__ pW0,
    const float* __restrict__ b0, const u16* __restrict__ pW1,
    const float* __restrict__ b1, float* __restrict__ out)
{
    __shared__ u16 sH[2 * 32 * HR];
    const int tid = threadIdx.x;
    const int wave = tid >> 6, lane = tid & 63;
    const int l15 = lane & 15, quad = lane >> 4;
    const int n0 = blockIdx.x * 64 + wave * 32;
    const int co = quad * 8;

    bf16x8 x[2][8];
    #pragma unroll
    for (int m = 0; m < 2; ++m) {
        int node = n0 + m * 16 + l15;
        int cn = (node < NN) ? node : 0;
        #pragma unroll
        for (int kt = 0; kt < 4; ++kt) {   // cols 0..127: agg fp32 -> bf16
            const float* p = agg + (size_t)cn * DD + kt * 32 + co;
            float4 u = *(const float4*)p;
            float4 v = *(const float4*)(p + 4);
            u32x4 q;
            q[0] = pk2(u.x, u.y); q[1] = pk2(u.z, u.w);
            q[2] = pk2(v.x, v.y); q[3] = pk2(v.z, v.w);
            x[m][kt] = __builtin_bit_cast(bf16x8, q);
        }
        #pragma unroll
        for (int kt = 0; kt < 4; ++kt)     // cols 128..255: nf bf16
            x[m][4 + kt] = ldbf8(nf16 + (size_t)cn * DD + kt * 32 + co);
    }

    u16* myH = sH + wave * 32 * HR;
    for (int nt = 0; nt < 16; ++nt) {
        const u16* wp = pW0 + nt * 8 * 512 + lane * 8;
        f32x4 c0 = {0.f,0.f,0.f,0.f}, c1 = {0.f,0.f,0.f,0.f};
        #pragma unroll
        for (int kt = 0; kt < 8; ++kt) {
            bf16x8 b = ldbf8(wp + kt * 512);
            c0 = __builtin_amdgcn_mfma_f32_16x16x32_bf16(x[0][kt], b, c0, 0, 0, 0);
            c1 = __builtin_amdgcn_mfma_f32_16x16x32_bf16(x[1][kt], b, c1, 0, 0, 0);
        }
        float bias = b0[nt * 16 + l15];
        #pragma unroll
        for (int i = 0; i < 4; ++i) {
            myH[(quad * 4 + i) * HR + nt * 16 + l15]      = f2bf(fmaxf(c0[i] + bias, 0.f));
            myH[(16 + quad * 4 + i) * HR + nt * 16 + l15] = f2bf(fmaxf(c1[i] + bias, 0.f));
        }
    }
    // H rows are wave-private; in-wave DS ordering -> no barrier.
    for (int n = 0; n < 8; ++n) {
        f32x4 c0 = {0.f,0.f,0.f,0.f}, c1 = {0.f,0.f,0.f,0.f};
        #pragma unroll
        for (int kt = 0; kt < 8; ++kt) {
            const u16* h0p = myH + l15 * HR + kt * 32 + co;
            const u16* h1p = myH + (16 + l15) * HR + kt * 32 + co;
            u16x4 a0 = *(const u16x4*)h0p;
            u16x4 a1 = *(const u16x4*)(h0p + 4);
            u16x4 b0v = *(const u16x4*)h1p;
            u16x4 b1v = *(const u16x4*)(h1p + 4);
            u16x8 hh0, hh1;
            hh0[0]=a0[0]; hh0[1]=a0[1]; hh0[2]=a0[2]; hh0[3]=a0[3];
            hh0[4]=a1[0]; hh0[5]=a1[1]; hh0[6]=a1[2]; hh0[7]=a1[3];
            hh1[0]=b0v[0]; hh1[1]=b0v[1]; hh1[2]=b0v[2]; hh1[3]=b0v[3];
            hh1[4]=b1v[0]; hh1[5]=b1v[1]; hh1[6]=b1v[2]; hh1[7]=b1v[3];
            bf16x8 b = ldbf8(pW1 + (n * 8 + kt) * 512 + lane * 8);
            c0 = __builtin_amdgcn_mfma_f32_16x16x32_bf16(__builtin_bit_cast(bf16x8, hh0), b, c0, 0, 0, 0);
            c1 = __builtin_amdgcn_mfma_f32_16x16x32_bf16(__builtin_bit_cast(bf16x8, hh1), b, c1, 0, 0, 0);
        }
        float bias = b1[n * 16 + l15];
        #pragma unroll
        for (int i = 0; i < 4; ++i) {
            int r0 = n0 + quad * 4 + i;
            int r1 = n0 + 16 + quad * 4 + i;
            if (r0 < NN) {
                int idx = r0 * DD + n * 16 + l15;
                out[idx] = nf32[idx] + fmaxf(c0[i] + bias, 0.f);
            }
            if (r1 < NN) {
                int idx = r1 * DD + n * 16 + l15;
                out[idx] = nf32[idx] + fmaxf(c1[i] + bias, 0.f);
            }
        }
    }
}

extern "C" void kernel_launch(void* const* d_in, const int* in_sizes, int n_in,
                              void* d_out, int out_size, void* d_ws, size_t ws_size,
                              hipStream_t stream)
{
    const float* nf  = (const float*)d_in[0];
    const int* fidx  = (const int*)d_in[1];
    const int* tidx  = (const int*)d_in[2];
    const float* mW0 = (const float*)d_in[3];
    const float* mb0 = (const float*)d_in[4];
    const float* mW1 = (const float*)d_in[5];
    const float* mb1 = (const float*)d_in[6];
    const float* uW0 = (const float*)d_in[7];
    const float* ub0 = (const float*)d_in[8];
    const float* uW1 = (const float*)d_in[9];
    const float* ub1 = (const float*)d_in[10];
    float* out = (float*)d_out;

    char* ws = (char*)d_ws;
    u16*   nf16  = (u16*)ws;   ws += (size_t)NN * DD * 2;        // 12.8 MB
    float* agg   = (float*)ws; ws += (size_t)NN * DD * 4;        // 25.6 MB
    u16*   P2    = (u16*)ws;   ws += (size_t)NN * 512 * 2;       // 51.2 MB
    u16*   pWcat = (u16*)ws;   ws += 128 * 512 * 2;
    u16*   pmW1  = (u16*)ws;   ws += 256 * 128 * 2;
    u16*   puW0  = (u16*)ws;   ws += 256 * 256 * 2;
    u16*   puW1  = (u16*)ws;   ws += 256 * 128 * 2;

    k_prep<<<7019, 256, 0, stream>>>(nf, nf16, agg, mW0, pWcat, mW1, pmW1, uW0, puW0, uW1, puW1);
    k_pgemm<<<(NN + 95) / 96, 192, 0, stream>>>(nf16, mb0, pWcat, P2);
    k_edges<<<NE / 96, 192, 0, stream>>>(P2, fidx, tidx, pmW1, mb1, agg);
    k_update<<<(NN + 63) / 64, 128, 0, stream>>>(agg, nf16, nf, puW0, ub0, puW1, ub1, out);
}